// Round 4
// baseline (416.031 us; speedup 1.0000x reference)
//
#include <hip/hip_runtime.h>
#include <hip/hip_bf16.h>
#include <math.h>

// Problem constants
#define BATCH 2
#define SLEN  2048
#define DIN   1024
#define DMODEL 1024
#define NHEAD 16
#define HD    64
#define E3    3072   // 3*DMODEL, row width of qkv

typedef unsigned short us;
typedef __attribute__((ext_vector_type(8))) __bf16 bf16x8;
typedef __attribute__((ext_vector_type(8))) unsigned short us8;
typedef __attribute__((ext_vector_type(4))) float f32x4;

// 0.125 (1/sqrt(HD)) * log2(e): folded into Q at qkv-GEMM epilogue so the
// attention softmax is a bare exp2 of the raw MFMA score.
#define QSCALE 0.18033688011112042f

__device__ __forceinline__ unsigned short bf16rne(float x) {
    unsigned int u = __float_as_uint(x);
    u += 0x7FFFu + ((u >> 16) & 1u);
    return (unsigned short)(u >> 16);
}
__device__ __forceinline__ float bf16tof(unsigned short h) {
    return __uint_as_float(((unsigned int)h) << 16);
}

// async 16B global->LDS (lane i deposits at ldsbase + i*16)
#define GLL16(g, l)                                                                     \
    __builtin_amdgcn_global_load_lds((const __attribute__((address_space(1))) unsigned int*)(g), \
                                     (__attribute__((address_space(3))) unsigned int*)(l), 16, 0, 0)

// ---------------- split conversion: fp32 -> bf16 hi + bf16 lo planes ----------------
__global__ __launch_bounds__(256) void cvt_split(const float* __restrict__ src,
                                                 us* __restrict__ hi, us* __restrict__ lo, int n)
{
    const int i = (blockIdx.x * 256 + threadIdx.x) * 8;
    if (i >= n) return;
    const float4 f0 = *(const float4*)&src[i];
    const float4 f1 = *(const float4*)&src[i + 4];
    const float v[8] = {f0.x, f0.y, f0.z, f0.w, f1.x, f1.y, f1.z, f1.w};
    us8 h, l;
#pragma unroll
    for (int j = 0; j < 8; ++j) {
        const us hh = bf16rne(v[j]);
        h[j] = hh;
        l[j] = bf16rne(v[j] - bf16tof(hh));
    }
    *(us8*)&hi[i] = h;
    *(us8*)&lo[i] = l;
}

// ---------------- split-bf16 MFMA GEMM ----------------
// C = (Ahi+Alo)(Bhi+Blo)^T + bias ~= Ahi.Bhi + Ahi.Blo + Alo.Bhi
// 128x128 tile, BK=32, 256 thr = 4 waves (2x2), 4x4 16x16 tiles per wave.
// QKV_OUT: write bf16 and pre-scale Q columns (col%192 < 64) by QSCALE.
template <bool QKV_OUT>
__global__ __launch_bounds__(256) void gemm_split(
    const us* __restrict__ Ahi, const us* __restrict__ Alo,
    const us* __restrict__ Bhi, const us* __restrict__ Blo,
    const float* __restrict__ bias, void* __restrict__ Cout,
    int M, int N, int K)
{
    __shared__ __align__(16) us AsH[128 * 32];
    __shared__ __align__(16) us AsL[128 * 32];
    __shared__ __align__(16) us BsH[128 * 32];
    __shared__ __align__(16) us BsL[128 * 32];

    const int t    = threadIdx.x;
    const int lane = t & 63;
    const int w    = t >> 6;
    const int ml   = lane & 15;
    const int quad = lane >> 4;
    const int wm   = w >> 1;
    const int wn   = w & 1;

    const int m0 = blockIdx.y * 128;
    const int n0 = blockIdx.x * 128;

    const int srow = (lane >> 2);
    const int scol = (lane & 3) * 8;

    const us* pAh = Ahi + (size_t)(m0 + w * 32 + srow) * K + scol;
    const us* pAl = Alo + (size_t)(m0 + w * 32 + srow) * K + scol;
    const us* pBh = Bhi + (size_t)(n0 + w * 32 + srow) * K + scol;
    const us* pBl = Blo + (size_t)(n0 + w * 32 + srow) * K + scol;
    const size_t rstep = (size_t)16 * K;

    us* lAh0 = &AsH[(w * 32) * 32];
    us* lAh1 = &AsH[(w * 32 + 16) * 32];
    us* lAl0 = &AsL[(w * 32) * 32];
    us* lAl1 = &AsL[(w * 32 + 16) * 32];
    us* lBh0 = &BsH[(w * 32) * 32];
    us* lBh1 = &BsH[(w * 32 + 16) * 32];
    us* lBl0 = &BsL[(w * 32) * 32];
    us* lBl1 = &BsL[(w * 32 + 16) * 32];

    f32x4 acc[4][4];
#pragma unroll
    for (int i = 0; i < 4; ++i)
#pragma unroll
        for (int j = 0; j < 4; ++j) {
            acc[i][j][0] = 0.f; acc[i][j][1] = 0.f; acc[i][j][2] = 0.f; acc[i][j][3] = 0.f;
        }

    for (int k0 = 0; k0 < K; k0 += 32) {
        __syncthreads();
        GLL16(pAh + k0, lAh0); GLL16(pAh + k0 + rstep, lAh1);
        GLL16(pAl + k0, lAl0); GLL16(pAl + k0 + rstep, lAl1);
        GLL16(pBh + k0, lBh0); GLL16(pBh + k0 + rstep, lBh1);
        GLL16(pBl + k0, lBl0); GLL16(pBl + k0 + rstep, lBl1);
        __syncthreads();

        bf16x8 ah[4], al[4];
#pragma unroll
        for (int i = 0; i < 4; ++i) {
            ah[i] = __builtin_bit_cast(bf16x8, *(const us8*)&AsH[(wm * 64 + i * 16 + ml) * 32 + quad * 8]);
            al[i] = __builtin_bit_cast(bf16x8, *(const us8*)&AsL[(wm * 64 + i * 16 + ml) * 32 + quad * 8]);
        }
#pragma unroll
        for (int j = 0; j < 4; ++j) {
            const bf16x8 bh = __builtin_bit_cast(bf16x8, *(const us8*)&BsH[(wn * 64 + j * 16 + ml) * 32 + quad * 8]);
            const bf16x8 bl = __builtin_bit_cast(bf16x8, *(const us8*)&BsL[(wn * 64 + j * 16 + ml) * 32 + quad * 8]);
#pragma unroll
            for (int i = 0; i < 4; ++i) {
                acc[i][j] = __builtin_amdgcn_mfma_f32_16x16x32_bf16(ah[i], bh, acc[i][j], 0, 0, 0);
                acc[i][j] = __builtin_amdgcn_mfma_f32_16x16x32_bf16(ah[i], bl, acc[i][j], 0, 0, 0);
                acc[i][j] = __builtin_amdgcn_mfma_f32_16x16x32_bf16(al[i], bh, acc[i][j], 0, 0, 0);
            }
        }
    }

    float bj[4], cs[4];
#pragma unroll
    for (int j = 0; j < 4; ++j) {
        const int col = n0 + wn * 64 + j * 16 + ml;
        bj[j] = bias[col];
        cs[j] = (QKV_OUT && (col % 192) < 64) ? QSCALE : 1.0f;
    }

#pragma unroll
    for (int i = 0; i < 4; ++i) {
#pragma unroll
        for (int r = 0; r < 4; ++r) {
            const size_t rowoff = (size_t)(m0 + wm * 64 + i * 16 + quad * 4 + r) * N;
#pragma unroll
            for (int j = 0; j < 4; ++j) {
                const int col = n0 + wn * 64 + j * 16 + ml;
                const float v = (acc[i][j][r] + bj[j]) * cs[j];
                if (QKV_OUT) ((us*)Cout)[rowoff + col] = bf16rne(v);
                else         ((float*)Cout)[rowoff + col] = v;
            }
        }
    }
}

// ---------------- MFMA flash attention, no-max softmax ----------------
// 8 waves x 16 q = 128 queries/block; 64-key chunks; Q pre-scaled so
// p = exp2(score). l accumulated by a ones-B MFMA. Qs and Ps share LDS
// (wave w's P rows == its own Q rows, read into regs before first use).
#define AW  8
#define ABQ 128
#define ACH 64
#define LQ  72    // LDS row stride in bf16 elems (36 words)

__global__ __launch_bounds__(512, 8) void attn_mfma(
    const us* __restrict__ qkvb, us* __restrict__ vHi, us* __restrict__ vLo)
{
    __shared__ __align__(16) us QPs[ABQ * LQ];   // Q tile, then per-wave P scratch
    __shared__ __align__(16) us Ks[ACH * LQ];
    __shared__ __align__(16) us Vt[HD * LQ];     // Vt[dim][key]

    const int t    = threadIdx.x;
    const int lane = t & 63;
    const int w    = t >> 6;
    const int ml   = lane & 15;
    const int quad = lane >> 4;

    const int bh = blockIdx.y;
    const int b  = bh >> 4;
    const int h  = bh & 15;
    const int q0 = blockIdx.x * ABQ;

    const size_t base = (size_t)b * SLEN * E3;
    const int qoff = h * 192;

    // stage Q (128 x 64 bf16); wave w writes exactly rows [16w,16w+16)
    {
        const int row = t >> 2;
        const int seg = (t & 3) * 16;
        const us* g = &qkvb[base + (size_t)(q0 + row) * E3 + qoff + seg];
        *(us8*)&QPs[row * LQ + seg]     = *(const us8*)(g);
        *(us8*)&QPs[row * LQ + seg + 8] = *(const us8*)(g + 8);
    }
    __syncthreads();

    // hoist Q fragments to registers (frees QPs rows for P scratch)
    const bf16x8 aq0 = __builtin_bit_cast(bf16x8, *(const us8*)&QPs[(w * 16 + ml) * LQ + quad * 8]);
    const bf16x8 aq1 = __builtin_bit_cast(bf16x8, *(const us8*)&QPs[(w * 16 + ml) * LQ + 32 + quad * 8]);

    us8 ones_u;
#pragma unroll
    for (int i = 0; i < 8; ++i) ones_u[i] = 0x3F80;  // bf16 1.0
    const bf16x8 ones = __builtin_bit_cast(bf16x8, ones_u);

    f32x4 O[4];
    f32x4 lacc = {0.f, 0.f, 0.f, 0.f};
#pragma unroll
    for (int nt = 0; nt < 4; ++nt) { O[nt][0] = 0.f; O[nt][1] = 0.f; O[nt][2] = 0.f; O[nt][3] = 0.f; }

    const int krow = t >> 3;        // 0..63 key within chunk (8 per wave)
    const int g8   = t & 7;         // dim-segment group
    const int kseg = g8 * 8;

    const int prow  = w * 16;                 // this wave's P region base row
    const int pswz  = (ml & 12) << 1;         // (ml>>2)<<3 : read-side swizzle
    const int wswz  = quad << 3;              // write-side swizzle

    for (int c = 0; c < SLEN / ACH; ++c) {
        // ---- stage K and V(transposed, rotated write order) ----
        {
            const us* gk = &qkvb[base + (size_t)(c * ACH + krow) * E3 + qoff + 64 + kseg];
            const us8 kv = *(const us8*)(gk);
            const us8 vv = *(const us8*)(gk + 64);
            *(us8*)&Ks[krow * LQ + kseg] = kv;
#pragma unroll
            for (int i = 0; i < 8; ++i) {
                const int j = (i + g8) & 7;           // rotation: banks disjoint per g8
                Vt[(kseg + j) * LQ + krow] = vv[j];
            }
        }
        __syncthreads();

        // ---- QK^T + exp2 + P store (per nt to keep regs lean) ----
#pragma unroll
        for (int nt = 0; nt < 4; ++nt) {
            const bf16x8 bk0 = __builtin_bit_cast(bf16x8, *(const us8*)&Ks[(nt * 16 + ml) * LQ + quad * 8]);
            const bf16x8 bk1 = __builtin_bit_cast(bf16x8, *(const us8*)&Ks[(nt * 16 + ml) * LQ + 32 + quad * 8]);
            f32x4 z = {0.f, 0.f, 0.f, 0.f};
            z = __builtin_amdgcn_mfma_f32_16x16x32_bf16(aq0, bk0, z, 0, 0, 0);
            z = __builtin_amdgcn_mfma_f32_16x16x32_bf16(aq1, bk1, z, 0, 0, 0);
            const int colw = ((nt * 16 + ml) ^ wswz);
#pragma unroll
            for (int r = 0; r < 4; ++r) {
                const float p = __builtin_amdgcn_exp2f(z[r]);   // score pre-scaled in Q
                QPs[(prow + quad * 4 + r) * LQ + colw] = bf16rne(p);
            }
        }

        // ---- PV + l accumulation ----
        const bf16x8 ap0 = __builtin_bit_cast(bf16x8, *(const us8*)&QPs[(prow + ml) * LQ + ((quad * 8) ^ pswz)]);
        const bf16x8 ap1 = __builtin_bit_cast(bf16x8, *(const us8*)&QPs[(prow + ml) * LQ + ((32 + quad * 8) ^ pswz)]);
        lacc = __builtin_amdgcn_mfma_f32_16x16x32_bf16(ap0, ones, lacc, 0, 0, 0);
        lacc = __builtin_amdgcn_mfma_f32_16x16x32_bf16(ap1, ones, lacc, 0, 0, 0);
#pragma unroll
        for (int nt = 0; nt < 4; ++nt) {
            const bf16x8 bv0 = __builtin_bit_cast(bf16x8, *(const us8*)&Vt[(nt * 16 + ml) * LQ + quad * 8]);
            const bf16x8 bv1 = __builtin_bit_cast(bf16x8, *(const us8*)&Vt[(nt * 16 + ml) * LQ + 32 + quad * 8]);
            O[nt] = __builtin_amdgcn_mfma_f32_16x16x32_bf16(ap0, bv0, O[nt], 0, 0, 0);
            O[nt] = __builtin_amdgcn_mfma_f32_16x16x32_bf16(ap1, bv1, O[nt], 0, 0, 0);
        }
        __syncthreads();   // all waves done with Ks/Vt before next staging
    }

    // ---- epilogue: normalize, split to hi/lo planes ----
#pragma unroll
    for (int r = 0; r < 4; ++r) {
        const float rl = 1.0f / lacc[r];
        const int q = q0 + w * 16 + quad * 4 + r;
#pragma unroll
        for (int nt = 0; nt < 4; ++nt) {
            const float o = O[nt][r] * rl;
            const us hi = bf16rne(o);
            const size_t idx = (size_t)(b * SLEN + q) * DMODEL + h * HD + nt * 16 + ml;
            vHi[idx] = hi;
            vLo[idx] = bf16rne(o - bf16tof(hi));
        }
    }
}

// ---------------- launch ----------------
extern "C" void kernel_launch(void* const* d_in, const int* in_sizes, int n_in,
                              void* d_out, int out_size, void* d_ws, size_t ws_size,
                              hipStream_t stream) {
    const float* x     = (const float*)d_in[0];
    const float* w_qkv = (const float*)d_in[1];
    const float* b_qkv = (const float*)d_in[2];
    const float* w_o   = (const float*)d_in[3];
    const float* b_o   = (const float*)d_in[4];
    float* out = (float*)d_out;

    const int M   = BATCH * SLEN;        // 4096
    const int XN  = M * DIN;
    const int WQN = E3 * DIN;
    const int WON = DMODEL * DMODEL;
    const size_t QKVN = (size_t)BATCH * SLEN * E3;

    us* qkvb = (us*)d_ws;
    us* xHi  = qkvb + QKVN;
    us* xLo  = xHi + XN;
    us* wHi  = xLo + XN;
    us* wLo  = wHi + WQN;

    cvt_split<<<dim3(XN / 2048), 256, 0, stream>>>(x, xHi, xLo, XN);
    cvt_split<<<dim3(WQN / 2048), 256, 0, stream>>>(w_qkv, wHi, wLo, WQN);

    // qkv (bf16, Q cols pre-scaled by QSCALE)
    gemm_split<true><<<dim3(E3 / 128, M / 128), 256, 0, stream>>>(
        xHi, xLo, wHi, wLo, b_qkv, qkvb, M, E3, DIN);

    us* vHi = xHi;
    us* vLo = xLo;
    attn_mfma<<<dim3(SLEN / ABQ, BATCH * NHEAD), 512, 0, stream>>>(qkvb, vHi, vLo);

    us* woHi = wHi;
    us* woLo = wHi + WON;
    cvt_split<<<dim3(WON / 2048), 256, 0, stream>>>(w_o, woHi, woLo, WON);

    gemm_split<false><<<dim3(DMODEL / 128, M / 128), 256, 0, stream>>>(
        vHi, vLo, woHi, woLo, b_o, out, M, DMODEL, DMODEL);
}

// Round 5
// 311.302 us; speedup vs baseline: 1.3364x; 1.3364x over previous
//
#include <hip/hip_runtime.h>
#include <hip/hip_bf16.h>
#include <math.h>

// Problem constants
#define BATCH 2
#define SLEN  2048
#define DIN   1024
#define DMODEL 1024
#define NHEAD 16
#define HD    64
#define E3    3072   // 3*DMODEL, row width of qkv

typedef unsigned short us;
typedef __attribute__((ext_vector_type(8))) __bf16 bf16x8;
typedef __attribute__((ext_vector_type(8))) unsigned short us8;
typedef __attribute__((ext_vector_type(4))) unsigned short us4;
typedef __attribute__((ext_vector_type(4))) float f32x4;

// 0.125 (1/sqrt(HD)) * log2(e): folded into Q at qkv-GEMM epilogue so the
// attention softmax is a bare exp2 of the raw MFMA score.
#define QSCALE 0.18033688011112042f

__device__ __forceinline__ unsigned short bf16rne(float x) {
    unsigned int u = __float_as_uint(x);
    u += 0x7FFFu + ((u >> 16) & 1u);
    return (unsigned short)(u >> 16);
}
__device__ __forceinline__ float bf16tof(unsigned short h) {
    return __uint_as_float(((unsigned int)h) << 16);
}

// async 16B global->LDS (lane i deposits at ldsbase + i*16)
#define GLL16(g, l)                                                                     \
    __builtin_amdgcn_global_load_lds((const __attribute__((address_space(1))) unsigned int*)(g), \
                                     (__attribute__((address_space(3))) unsigned int*)(l), 16, 0, 0)

// ---------------- split conversion: fp32 -> bf16 hi + bf16 lo planes ----------------
__global__ __launch_bounds__(256) void cvt_split(const float* __restrict__ src,
                                                 us* __restrict__ hi, us* __restrict__ lo, int n)
{
    const int i = (blockIdx.x * 256 + threadIdx.x) * 8;
    if (i >= n) return;
    const float4 f0 = *(const float4*)&src[i];
    const float4 f1 = *(const float4*)&src[i + 4];
    const float v[8] = {f0.x, f0.y, f0.z, f0.w, f1.x, f1.y, f1.z, f1.w};
    us8 h, l;
#pragma unroll
    for (int j = 0; j < 8; ++j) {
        const us hh = bf16rne(v[j]);
        h[j] = hh;
        l[j] = bf16rne(v[j] - bf16tof(hh));
    }
    *(us8*)&hi[i] = h;
    *(us8*)&lo[i] = l;
}

// ---------------- split-bf16 MFMA GEMM ----------------
// C = (Ahi+Alo)(Bhi+Blo)^T + bias ~= Ahi.Bhi + Ahi.Blo + Alo.Bhi
// 128x128 tile, BK=32, 256 thr = 4 waves (2x2), 4x4 16x16 tiles per wave.
// QKV_OUT: write bf16 and pre-scale Q columns (col%192 < 64) by QSCALE.
template <bool QKV_OUT>
__global__ __launch_bounds__(256) void gemm_split(
    const us* __restrict__ Ahi, const us* __restrict__ Alo,
    const us* __restrict__ Bhi, const us* __restrict__ Blo,
    const float* __restrict__ bias, void* __restrict__ Cout,
    int M, int N, int K)
{
    __shared__ __align__(16) us AsH[128 * 32];
    __shared__ __align__(16) us AsL[128 * 32];
    __shared__ __align__(16) us BsH[128 * 32];
    __shared__ __align__(16) us BsL[128 * 32];

    const int t    = threadIdx.x;
    const int lane = t & 63;
    const int w    = t >> 6;
    const int ml   = lane & 15;
    const int quad = lane >> 4;
    const int wm   = w >> 1;
    const int wn   = w & 1;

    const int m0 = blockIdx.y * 128;
    const int n0 = blockIdx.x * 128;

    const int srow = (lane >> 2);
    const int scol = (lane & 3) * 8;

    const us* pAh = Ahi + (size_t)(m0 + w * 32 + srow) * K + scol;
    const us* pAl = Alo + (size_t)(m0 + w * 32 + srow) * K + scol;
    const us* pBh = Bhi + (size_t)(n0 + w * 32 + srow) * K + scol;
    const us* pBl = Blo + (size_t)(n0 + w * 32 + srow) * K + scol;
    const size_t rstep = (size_t)16 * K;

    us* lAh0 = &AsH[(w * 32) * 32];
    us* lAh1 = &AsH[(w * 32 + 16) * 32];
    us* lAl0 = &AsL[(w * 32) * 32];
    us* lAl1 = &AsL[(w * 32 + 16) * 32];
    us* lBh0 = &BsH[(w * 32) * 32];
    us* lBh1 = &BsH[(w * 32 + 16) * 32];
    us* lBl0 = &BsL[(w * 32) * 32];
    us* lBl1 = &BsL[(w * 32 + 16) * 32];

    f32x4 acc[4][4];
#pragma unroll
    for (int i = 0; i < 4; ++i)
#pragma unroll
        for (int j = 0; j < 4; ++j) {
            acc[i][j][0] = 0.f; acc[i][j][1] = 0.f; acc[i][j][2] = 0.f; acc[i][j][3] = 0.f;
        }

    for (int k0 = 0; k0 < K; k0 += 32) {
        __syncthreads();
        GLL16(pAh + k0, lAh0); GLL16(pAh + k0 + rstep, lAh1);
        GLL16(pAl + k0, lAl0); GLL16(pAl + k0 + rstep, lAl1);
        GLL16(pBh + k0, lBh0); GLL16(pBh + k0 + rstep, lBh1);
        GLL16(pBl + k0, lBl0); GLL16(pBl + k0 + rstep, lBl1);
        __syncthreads();

        bf16x8 ah[4], al[4];
#pragma unroll
        for (int i = 0; i < 4; ++i) {
            ah[i] = __builtin_bit_cast(bf16x8, *(const us8*)&AsH[(wm * 64 + i * 16 + ml) * 32 + quad * 8]);
            al[i] = __builtin_bit_cast(bf16x8, *(const us8*)&AsL[(wm * 64 + i * 16 + ml) * 32 + quad * 8]);
        }
#pragma unroll
        for (int j = 0; j < 4; ++j) {
            const bf16x8 bh = __builtin_bit_cast(bf16x8, *(const us8*)&BsH[(wn * 64 + j * 16 + ml) * 32 + quad * 8]);
            const bf16x8 bl = __builtin_bit_cast(bf16x8, *(const us8*)&BsL[(wn * 64 + j * 16 + ml) * 32 + quad * 8]);
#pragma unroll
            for (int i = 0; i < 4; ++i) {
                acc[i][j] = __builtin_amdgcn_mfma_f32_16x16x32_bf16(ah[i], bh, acc[i][j], 0, 0, 0);
                acc[i][j] = __builtin_amdgcn_mfma_f32_16x16x32_bf16(ah[i], bl, acc[i][j], 0, 0, 0);
                acc[i][j] = __builtin_amdgcn_mfma_f32_16x16x32_bf16(al[i], bh, acc[i][j], 0, 0, 0);
            }
        }
    }

    float bj[4], cs[4];
#pragma unroll
    for (int j = 0; j < 4; ++j) {
        const int col = n0 + wn * 64 + j * 16 + ml;
        bj[j] = bias[col];
        cs[j] = (QKV_OUT && (col % 192) < 64) ? QSCALE : 1.0f;
    }

#pragma unroll
    for (int i = 0; i < 4; ++i) {
#pragma unroll
        for (int r = 0; r < 4; ++r) {
            const size_t rowoff = (size_t)(m0 + wm * 64 + i * 16 + quad * 4 + r) * N;
#pragma unroll
            for (int j = 0; j < 4; ++j) {
                const int col = n0 + wn * 64 + j * 16 + ml;
                const float v = (acc[i][j][r] + bj[j]) * cs[j];
                if (QKV_OUT) ((us*)Cout)[rowoff + col] = bf16rne(v);
                else         ((float*)Cout)[rowoff + col] = v;
            }
        }
    }
}

// ---------------- MFMA flash attention, transposed-score formulation ----------------
// 8 waves x 16 q = 128 queries/block; 64-key chunks; Q pre-scaled so p = exp2(score).
// S^T = K.Q^T  (A=K-frag, B=Q-frag; same Q registers serve as B operand) puts 4
// CONSECUTIVE KEYS per lane -> P store is 4 packed b64 writes, conflict-free.
// PV as O^T = V^T.P^T (A=Vt rows, B=P rows read b128). l via mfma(ones, P^T).
// Wave w's P scratch = its own Q rows of QPs (Q hoisted to regs first).
#define AW  8
#define ABQ 128
#define ACH 64
#define LQ  72    // LDS row stride in bf16 elems (36 words; stride-36 rows are
                  // conflict-free for the b64-write / b128-read patterns here)

__global__ __launch_bounds__(512, 4) void attn_mfma(
    const us* __restrict__ qkvb, us* __restrict__ vHi, us* __restrict__ vLo)
{
    __shared__ __align__(16) us QPs[ABQ * LQ];   // Q tile, then per-wave P^T-ish scratch
    __shared__ __align__(16) us Ks[ACH * LQ];
    __shared__ __align__(16) us Vt[HD * LQ];     // Vt[dim][key]

    const int t    = threadIdx.x;
    const int lane = t & 63;
    const int w    = t >> 6;
    const int ml   = lane & 15;
    const int quad = lane >> 4;

    const int bh = blockIdx.y;
    const int b  = bh >> 4;
    const int h  = bh & 15;
    const int q0 = blockIdx.x * ABQ;

    const size_t base = (size_t)b * SLEN * E3;
    const int qoff = h * 192;

    // stage Q (128 x 64 bf16); wave w writes exactly rows [16w,16w+16)
    {
        const int row = t >> 2;
        const int seg = (t & 3) * 16;
        const us* g = &qkvb[base + (size_t)(q0 + row) * E3 + qoff + seg];
        *(us8*)&QPs[row * LQ + seg]     = *(const us8*)(g);
        *(us8*)&QPs[row * LQ + seg + 8] = *(const us8*)(g + 8);
    }
    __syncthreads();

    // hoist Q fragments to registers (frees QPs rows for P scratch).
    // Element map Q[q=ml][d=quad*8+j] works as BOTH A- and B-operand fragment.
    const bf16x8 aq0 = __builtin_bit_cast(bf16x8, *(const us8*)&QPs[(w * 16 + ml) * LQ + quad * 8]);
    const bf16x8 aq1 = __builtin_bit_cast(bf16x8, *(const us8*)&QPs[(w * 16 + ml) * LQ + 32 + quad * 8]);

    us8 ones_u;
#pragma unroll
    for (int i = 0; i < 8; ++i) ones_u[i] = 0x3F80;  // bf16 1.0
    const bf16x8 ones = __builtin_bit_cast(bf16x8, ones_u);

    f32x4 O[4];               // O^T tiles: row = d (quad*4+r), col = q (ml)
    f32x4 lacc = {0.f, 0.f, 0.f, 0.f};
#pragma unroll
    for (int nt = 0; nt < 4; ++nt) { O[nt][0] = 0.f; O[nt][1] = 0.f; O[nt][2] = 0.f; O[nt][3] = 0.f; }

    const int krow = t >> 3;        // 0..63 key within chunk (8 per wave)
    const int g8   = t & 7;         // dim-segment group
    const int kseg = g8 * 8;

    const int prow = w * 16;        // this wave's P region base row (row = q = ml)

    for (int c = 0; c < SLEN / ACH; ++c) {
        // ---- stage K (row-major) and V (transposed, rotated write order) ----
        {
            const us* gk = &qkvb[base + (size_t)(c * ACH + krow) * E3 + qoff + 64 + kseg];
            const us8 kv = *(const us8*)(gk);
            const us8 vv = *(const us8*)(gk + 64);
            *(us8*)&Ks[krow * LQ + kseg] = kv;
#pragma unroll
            for (int i = 0; i < 8; ++i) {
                const int j = (i + g8) & 7;           // rotation: banks disjoint per g8
                Vt[(kseg + j) * LQ + krow] = vv[j];
            }
        }
        __syncthreads();

        // ---- S^T = K.Q^T, exp2, packed b64 P store: P[q=ml][key] ----
#pragma unroll
        for (int nt = 0; nt < 4; ++nt) {
            const bf16x8 ak0 = __builtin_bit_cast(bf16x8, *(const us8*)&Ks[(nt * 16 + ml) * LQ + quad * 8]);
            const bf16x8 ak1 = __builtin_bit_cast(bf16x8, *(const us8*)&Ks[(nt * 16 + ml) * LQ + 32 + quad * 8]);
            f32x4 z = {0.f, 0.f, 0.f, 0.f};
            z = __builtin_amdgcn_mfma_f32_16x16x32_bf16(ak0, aq0, z, 0, 0, 0);
            z = __builtin_amdgcn_mfma_f32_16x16x32_bf16(ak1, aq1, z, 0, 0, 0);
            // lane holds S^T[key = nt*16 + quad*4 + r][q = ml]
            us4 pp;
#pragma unroll
            for (int r = 0; r < 4; ++r) pp[r] = bf16rne(__builtin_amdgcn_exp2f(z[r]));
            *(us4*)&QPs[(prow + ml) * LQ + nt * 16 + quad * 4] = pp;
        }

        // ---- P^T B-frags (row-major P: 8 contiguous keys per lane) ----
        const bf16x8 pb0 = __builtin_bit_cast(bf16x8, *(const us8*)&QPs[(prow + ml) * LQ + quad * 8]);
        const bf16x8 pb1 = __builtin_bit_cast(bf16x8, *(const us8*)&QPs[(prow + ml) * LQ + 32 + quad * 8]);

        // ---- l row-sums via ones-A MFMA; O^T += V^T.P^T ----
        lacc = __builtin_amdgcn_mfma_f32_16x16x32_bf16(ones, pb0, lacc, 0, 0, 0);
        lacc = __builtin_amdgcn_mfma_f32_16x16x32_bf16(ones, pb1, lacc, 0, 0, 0);
#pragma unroll
        for (int nt = 0; nt < 4; ++nt) {
            const bf16x8 av0 = __builtin_bit_cast(bf16x8, *(const us8*)&Vt[(nt * 16 + ml) * LQ + quad * 8]);
            const bf16x8 av1 = __builtin_bit_cast(bf16x8, *(const us8*)&Vt[(nt * 16 + ml) * LQ + 32 + quad * 8]);
            O[nt] = __builtin_amdgcn_mfma_f32_16x16x32_bf16(av0, pb0, O[nt], 0, 0, 0);
            O[nt] = __builtin_amdgcn_mfma_f32_16x16x32_bf16(av1, pb1, O[nt], 0, 0, 0);
        }
        __syncthreads();   // all waves done with Ks/Vt before next staging
    }

    // ---- epilogue: O^T col q = ml; 4 consecutive d per (nt, lane) -> b64 stores ----
    const float rl = 1.0f / lacc[0];   // l[q=ml]; all rows of lacc identical
    const int q = q0 + w * 16 + ml;
    const size_t rowbase = (size_t)(b * SLEN + q) * DMODEL + h * HD;
#pragma unroll
    for (int nt = 0; nt < 4; ++nt) {
        us4 ho, lo;
#pragma unroll
        for (int r = 0; r < 4; ++r) {
            const float o = O[nt][r] * rl;
            const us hi = bf16rne(o);
            ho[r] = hi;
            lo[r] = bf16rne(o - bf16tof(hi));
        }
        const size_t idx = rowbase + nt * 16 + quad * 4;
        *(us4*)&vHi[idx] = ho;
        *(us4*)&vLo[idx] = lo;
    }
}

// ---------------- launch ----------------
extern "C" void kernel_launch(void* const* d_in, const int* in_sizes, int n_in,
                              void* d_out, int out_size, void* d_ws, size_t ws_size,
                              hipStream_t stream) {
    const float* x     = (const float*)d_in[0];
    const float* w_qkv = (const float*)d_in[1];
    const float* b_qkv = (const float*)d_in[2];
    const float* w_o   = (const float*)d_in[3];
    const float* b_o   = (const float*)d_in[4];
    float* out = (float*)d_out;

    const int M   = BATCH * SLEN;        // 4096
    const int XN  = M * DIN;
    const int WQN = E3 * DIN;
    const int WON = DMODEL * DMODEL;
    const size_t QKVN = (size_t)BATCH * SLEN * E3;

    us* qkvb = (us*)d_ws;
    us* xHi  = qkvb + QKVN;
    us* xLo  = xHi + XN;
    us* wHi  = xLo + XN;
    us* wLo  = wHi + WQN;

    cvt_split<<<dim3(XN / 2048), 256, 0, stream>>>(x, xHi, xLo, XN);
    cvt_split<<<dim3(WQN / 2048), 256, 0, stream>>>(w_qkv, wHi, wLo, WQN);

    // qkv (bf16, Q cols pre-scaled by QSCALE)
    gemm_split<true><<<dim3(E3 / 128, M / 128), 256, 0, stream>>>(
        xHi, xLo, wHi, wLo, b_qkv, qkvb, M, E3, DIN);

    us* vHi = xHi;
    us* vLo = xLo;
    attn_mfma<<<dim3(SLEN / ABQ, BATCH * NHEAD), 512, 0, stream>>>(qkvb, vHi, vLo);

    us* woHi = wHi;
    us* woLo = wHi + WON;
    cvt_split<<<dim3(WON / 2048), 256, 0, stream>>>(w_o, woHi, woLo, WON);

    gemm_split<false><<<dim3(DMODEL / 128, M / 128), 256, 0, stream>>>(
        vHi, vLo, woHi, woLo, b_o, out, M, DMODEL, DMODEL);
}

// Round 6
// 280.225 us; speedup vs baseline: 1.4846x; 1.1109x over previous
//
#include <hip/hip_runtime.h>
#include <hip/hip_bf16.h>
#include <math.h>

// Problem constants
#define BATCH 2
#define SLEN  2048
#define DIN   1024
#define DMODEL 1024
#define NHEAD 16
#define HD    64
#define E3    3072   // 3*DMODEL, row width of qkv

typedef unsigned short us;
typedef _Float16 f16;
typedef __attribute__((ext_vector_type(8))) _Float16 f16x8;
typedef __attribute__((ext_vector_type(8))) unsigned short us8;
typedef __attribute__((ext_vector_type(4))) unsigned short us4;
typedef __attribute__((ext_vector_type(4))) float f32x4;

// 0.125 (1/sqrt(HD)) * log2(e): folded into Q at qkv-GEMM epilogue so the
// attention softmax is a bare exp2 of the raw MFMA score.
#define QSCALE 0.18033688011112042f

__device__ __forceinline__ us f16bits(float x) {
    const f16 h = (f16)x;
    return __builtin_bit_cast(us, h);
}
__device__ __forceinline__ float f16tof(us b) {
    return (float)__builtin_bit_cast(f16, b);
}

// async 16B global->LDS (lane i deposits at ldsbase + i*16)
#define GLL16(g, l)                                                                     \
    __builtin_amdgcn_global_load_lds((const __attribute__((address_space(1))) unsigned int*)(g), \
                                     (__attribute__((address_space(3))) unsigned int*)(l), 16, 0, 0)

// ---------------- fp32 -> fp16 hi + fp16 lo planes (activations) ----------------
__global__ __launch_bounds__(256) void cvt_split_f16(const float* __restrict__ src,
                                                     us* __restrict__ hi, us* __restrict__ lo, int n)
{
    const int i = (blockIdx.x * 256 + threadIdx.x) * 8;
    if (i >= n) return;
    const float4 f0 = *(const float4*)&src[i];
    const float4 f1 = *(const float4*)&src[i + 4];
    const float v[8] = {f0.x, f0.y, f0.z, f0.w, f1.x, f1.y, f1.z, f1.w};
    us8 h, l;
#pragma unroll
    for (int j = 0; j < 8; ++j) {
        const us hh = f16bits(v[j]);
        h[j] = hh;
        l[j] = f16bits(v[j] - f16tof(hh));
    }
    *(us8*)&hi[i] = h;
    *(us8*)&lo[i] = l;
}

// ---------------- fp32 -> single fp16 (weights; two tensors in one launch) ----------------
__global__ __launch_bounds__(256) void cvt_f16_2(const float* __restrict__ a, us* __restrict__ oa, int na,
                                                 const float* __restrict__ b, us* __restrict__ ob)
{
    int i = (blockIdx.x * 256 + threadIdx.x) * 8;
    const float* s;
    us* o;
    if (i < na) { s = a; o = oa; }
    else        { s = b; o = ob; i -= na; }
    const float4 f0 = *(const float4*)&s[i];
    const float4 f1 = *(const float4*)&s[i + 4];
    const float v[8] = {f0.x, f0.y, f0.z, f0.w, f1.x, f1.y, f1.z, f1.w};
    us8 h;
#pragma unroll
    for (int j = 0; j < 8; ++j) h[j] = f16bits(v[j]);
    *(us8*)&o[i] = h;
}

// ---------------- split-fp16 MFMA GEMM (2 products) ----------------
// C = (Ahi+Alo)[M,K] * B[N,K]^T + bias ~= Ahi.B + Alo.B
// (A = activations split hi/lo fp16; B = weights single fp16, u=2^-11.)
// 128x128 tile, BK=32, 256 thr = 4 waves (2x2), 4x4 16x16 tiles per wave.
// QKV_OUT: write fp16 and pre-scale Q columns (col%192 < 64) by QSCALE.
template <bool QKV_OUT>
__global__ __launch_bounds__(256) void gemm_split(
    const us* __restrict__ Ahi, const us* __restrict__ Alo,
    const us* __restrict__ Bm,
    const float* __restrict__ bias, void* __restrict__ Cout,
    int M, int N, int K)
{
    __shared__ __align__(16) us AsH[128 * 32];
    __shared__ __align__(16) us AsL[128 * 32];
    __shared__ __align__(16) us Bs[128 * 32];

    const int t    = threadIdx.x;
    const int lane = t & 63;
    const int w    = t >> 6;
    const int ml   = lane & 15;
    const int quad = lane >> 4;
    const int wm   = w >> 1;
    const int wn   = w & 1;

    const int m0 = blockIdx.y * 128;
    const int n0 = blockIdx.x * 128;

    const int srow = (lane >> 2);
    const int scol = (lane & 3) * 8;

    const us* pAh = Ahi + (size_t)(m0 + w * 32 + srow) * K + scol;
    const us* pAl = Alo + (size_t)(m0 + w * 32 + srow) * K + scol;
    const us* pB  = Bm  + (size_t)(n0 + w * 32 + srow) * K + scol;
    const size_t rstep = (size_t)16 * K;

    us* lAh0 = &AsH[(w * 32) * 32];
    us* lAh1 = &AsH[(w * 32 + 16) * 32];
    us* lAl0 = &AsL[(w * 32) * 32];
    us* lAl1 = &AsL[(w * 32 + 16) * 32];
    us* lB0  = &Bs[(w * 32) * 32];
    us* lB1  = &Bs[(w * 32 + 16) * 32];

    f32x4 acc[4][4];
#pragma unroll
    for (int i = 0; i < 4; ++i)
#pragma unroll
        for (int j = 0; j < 4; ++j) {
            acc[i][j][0] = 0.f; acc[i][j][1] = 0.f; acc[i][j][2] = 0.f; acc[i][j][3] = 0.f;
        }

    for (int k0 = 0; k0 < K; k0 += 32) {
        __syncthreads();
        GLL16(pAh + k0, lAh0); GLL16(pAh + k0 + rstep, lAh1);
        GLL16(pAl + k0, lAl0); GLL16(pAl + k0 + rstep, lAl1);
        GLL16(pB + k0, lB0);   GLL16(pB + k0 + rstep, lB1);
        __syncthreads();

        f16x8 ah[4], al[4];
#pragma unroll
        for (int i = 0; i < 4; ++i) {
            ah[i] = __builtin_bit_cast(f16x8, *(const us8*)&AsH[(wm * 64 + i * 16 + ml) * 32 + quad * 8]);
            al[i] = __builtin_bit_cast(f16x8, *(const us8*)&AsL[(wm * 64 + i * 16 + ml) * 32 + quad * 8]);
        }
#pragma unroll
        for (int j = 0; j < 4; ++j) {
            const f16x8 b = __builtin_bit_cast(f16x8, *(const us8*)&Bs[(wn * 64 + j * 16 + ml) * 32 + quad * 8]);
#pragma unroll
            for (int i = 0; i < 4; ++i) {
                acc[i][j] = __builtin_amdgcn_mfma_f32_16x16x32_f16(ah[i], b, acc[i][j], 0, 0, 0);
                acc[i][j] = __builtin_amdgcn_mfma_f32_16x16x32_f16(al[i], b, acc[i][j], 0, 0, 0);
            }
        }
    }

    float bj[4], cs[4];
#pragma unroll
    for (int j = 0; j < 4; ++j) {
        const int col = n0 + wn * 64 + j * 16 + ml;
        bj[j] = bias[col];
        cs[j] = (QKV_OUT && (col % 192) < 64) ? QSCALE : 1.0f;
    }

#pragma unroll
    for (int i = 0; i < 4; ++i) {
#pragma unroll
        for (int r = 0; r < 4; ++r) {
            const size_t rowoff = (size_t)(m0 + wm * 64 + i * 16 + quad * 4 + r) * N;
#pragma unroll
            for (int j = 0; j < 4; ++j) {
                const int col = n0 + wn * 64 + j * 16 + ml;
                const float v = (acc[i][j][r] + bj[j]) * cs[j];
                if (QKV_OUT) ((us*)Cout)[rowoff + col] = f16bits(v);
                else         ((float*)Cout)[rowoff + col] = v;
            }
        }
    }
}

// ---------------- MFMA flash attention, transposed-score formulation (fp16) ----------------
// 8 waves x 16 q = 128 queries/block; 64-key chunks; Q pre-scaled so p = exp2(score).
// S^T = K.Q^T puts 4 CONSECUTIVE KEYS per lane -> packed b64 P stores.
// PV as O^T = V^T.P^T; l via mfma(ones, P^T). Wave w's P scratch = its own Q rows.
#define AW  8
#define ABQ 128
#define ACH 64
#define LQ  72    // LDS row stride in fp16 elems

__global__ __launch_bounds__(512, 4) void attn_mfma(
    const us* __restrict__ qkvh, us* __restrict__ vHi, us* __restrict__ vLo)
{
    __shared__ __align__(16) us QPs[ABQ * LQ];   // Q tile, then per-wave P scratch
    __shared__ __align__(16) us Ks[ACH * LQ];
    __shared__ __align__(16) us Vt[HD * LQ];     // Vt[dim][key]

    const int t    = threadIdx.x;
    const int lane = t & 63;
    const int w    = t >> 6;
    const int ml   = lane & 15;
    const int quad = lane >> 4;

    const int bh = blockIdx.y;
    const int b  = bh >> 4;
    const int h  = bh & 15;
    const int q0 = blockIdx.x * ABQ;

    const size_t base = (size_t)b * SLEN * E3;
    const int qoff = h * 192;

    // stage Q (128 x 64 fp16); wave w writes exactly rows [16w,16w+16)
    {
        const int row = t >> 2;
        const int seg = (t & 3) * 16;
        const us* g = &qkvh[base + (size_t)(q0 + row) * E3 + qoff + seg];
        *(us8*)&QPs[row * LQ + seg]     = *(const us8*)(g);
        *(us8*)&QPs[row * LQ + seg + 8] = *(const us8*)(g + 8);
    }
    __syncthreads();

    // hoist Q fragments to registers (frees QPs rows for P scratch)
    const f16x8 aq0 = __builtin_bit_cast(f16x8, *(const us8*)&QPs[(w * 16 + ml) * LQ + quad * 8]);
    const f16x8 aq1 = __builtin_bit_cast(f16x8, *(const us8*)&QPs[(w * 16 + ml) * LQ + 32 + quad * 8]);

    us8 ones_u;
#pragma unroll
    for (int i = 0; i < 8; ++i) ones_u[i] = 0x3C00;  // fp16 1.0
    const f16x8 ones = __builtin_bit_cast(f16x8, ones_u);

    f32x4 O[4];               // O^T tiles: row = d (quad*4+r), col = q (ml)
    f32x4 lacc = {0.f, 0.f, 0.f, 0.f};
#pragma unroll
    for (int nt = 0; nt < 4; ++nt) { O[nt][0] = 0.f; O[nt][1] = 0.f; O[nt][2] = 0.f; O[nt][3] = 0.f; }

    const int krow = t >> 3;        // 0..63 key within chunk (8 per wave)
    const int g8   = t & 7;         // dim-segment group
    const int kseg = g8 * 8;

    const int prow = w * 16;        // this wave's P region base row (row = q = ml)

    for (int c = 0; c < SLEN / ACH; ++c) {
        // ---- stage K (row-major) and V (transposed, rotated write order) ----
        {
            const us* gk = &qkvh[base + (size_t)(c * ACH + krow) * E3 + qoff + 64 + kseg];
            const us8 kv = *(const us8*)(gk);
            const us8 vv = *(const us8*)(gk + 64);
            *(us8*)&Ks[krow * LQ + kseg] = kv;
#pragma unroll
            for (int i = 0; i < 8; ++i) {
                const int j = (i + g8) & 7;           // rotation: banks disjoint per g8
                Vt[(kseg + j) * LQ + krow] = vv[j];
            }
        }
        __syncthreads();

        // ---- S^T = K.Q^T, exp2, packed b64 P store: P[q=ml][key] ----
#pragma unroll
        for (int nt = 0; nt < 4; ++nt) {
            const f16x8 ak0 = __builtin_bit_cast(f16x8, *(const us8*)&Ks[(nt * 16 + ml) * LQ + quad * 8]);
            const f16x8 ak1 = __builtin_bit_cast(f16x8, *(const us8*)&Ks[(nt * 16 + ml) * LQ + 32 + quad * 8]);
            f32x4 z = {0.f, 0.f, 0.f, 0.f};
            z = __builtin_amdgcn_mfma_f32_16x16x32_f16(ak0, aq0, z, 0, 0, 0);
            z = __builtin_amdgcn_mfma_f32_16x16x32_f16(ak1, aq1, z, 0, 0, 0);
            // lane holds S^T[key = nt*16 + quad*4 + r][q = ml]
            us4 pp;
#pragma unroll
            for (int r = 0; r < 4; ++r) pp[r] = f16bits(__builtin_amdgcn_exp2f(z[r]));
            *(us4*)&QPs[(prow + ml) * LQ + nt * 16 + quad * 4] = pp;
        }

        // ---- P^T B-frags (row-major P: 8 contiguous keys per lane) ----
        const f16x8 pb0 = __builtin_bit_cast(f16x8, *(const us8*)&QPs[(prow + ml) * LQ + quad * 8]);
        const f16x8 pb1 = __builtin_bit_cast(f16x8, *(const us8*)&QPs[(prow + ml) * LQ + 32 + quad * 8]);

        // ---- l row-sums via ones-A MFMA; O^T += V^T.P^T ----
        lacc = __builtin_amdgcn_mfma_f32_16x16x32_f16(ones, pb0, lacc, 0, 0, 0);
        lacc = __builtin_amdgcn_mfma_f32_16x16x32_f16(ones, pb1, lacc, 0, 0, 0);
#pragma unroll
        for (int nt = 0; nt < 4; ++nt) {
            const f16x8 av0 = __builtin_bit_cast(f16x8, *(const us8*)&Vt[(nt * 16 + ml) * LQ + quad * 8]);
            const f16x8 av1 = __builtin_bit_cast(f16x8, *(const us8*)&Vt[(nt * 16 + ml) * LQ + 32 + quad * 8]);
            O[nt] = __builtin_amdgcn_mfma_f32_16x16x32_f16(av0, pb0, O[nt], 0, 0, 0);
            O[nt] = __builtin_amdgcn_mfma_f32_16x16x32_f16(av1, pb1, O[nt], 0, 0, 0);
        }
        __syncthreads();   // all waves done with Ks/Vt before next staging
    }

    // ---- epilogue: O^T col q = ml; split fp16 hi/lo, b64 stores ----
    const float rl = 1.0f / lacc[0];   // l[q=ml]; all rows of lacc identical
    const int q = q0 + w * 16 + ml;
    const size_t rowbase = (size_t)(b * SLEN + q) * DMODEL + h * HD;
#pragma unroll
    for (int nt = 0; nt < 4; ++nt) {
        us4 ho, lo;
#pragma unroll
        for (int r = 0; r < 4; ++r) {
            const float o = O[nt][r] * rl;
            const us hi = f16bits(o);
            ho[r] = hi;
            lo[r] = f16bits(o - f16tof(hi));
        }
        const size_t idx = rowbase + nt * 16 + quad * 4;
        *(us4*)&vHi[idx] = ho;
        *(us4*)&vLo[idx] = lo;
    }
}

// ---------------- launch ----------------
extern "C" void kernel_launch(void* const* d_in, const int* in_sizes, int n_in,
                              void* d_out, int out_size, void* d_ws, size_t ws_size,
                              hipStream_t stream) {
    const float* x     = (const float*)d_in[0];
    const float* w_qkv = (const float*)d_in[1];
    const float* b_qkv = (const float*)d_in[2];
    const float* w_o   = (const float*)d_in[3];
    const float* b_o   = (const float*)d_in[4];
    float* out = (float*)d_out;

    const int M   = BATCH * SLEN;        // 4096
    const int XN  = M * DIN;             // 4,194,304
    const int WQN = E3 * DIN;            // 3,145,728
    const int WON = DMODEL * DMODEL;     // 1,048,576
    const size_t QKVN = (size_t)BATCH * SLEN * E3;

    us* qkvh = (us*)d_ws;                // fp16 qkv  [QKVN]
    us* xHi  = qkvh + QKVN;              // activations hi/lo (reused for vals)
    us* xLo  = xHi + XN;
    us* wq   = xLo + XN;                 // w_qkv fp16 [WQN]
    us* wo   = wq + WQN;                 // w_o  fp16 [WON]

    // 1) convert: x -> hi/lo split; both weight tensors -> single fp16 (one launch)
    cvt_split_f16<<<dim3(XN / 2048), 256, 0, stream>>>(x, xHi, xLo, XN);
    cvt_f16_2<<<dim3((WQN + WON) / 2048), 256, 0, stream>>>(w_qkv, wq, WQN, w_o, wo);

    // 2) qkv = x @ w_qkv^T + b_qkv  -> fp16 (Q cols pre-scaled by QSCALE)
    gemm_split<true><<<dim3(E3 / 128, M / 128), 256, 0, stream>>>(
        xHi, xLo, wq, b_qkv, qkvh, M, E3, DIN);

    // 3) attention -> vals hi/lo (reuse activation planes; x is dead)
    us* vHi = xHi;
    us* vLo = xLo;
    attn_mfma<<<dim3(SLEN / ABQ, BATCH * NHEAD), 512, 0, stream>>>(qkvh, vHi, vLo);

    // 4) out = vals @ w_o^T + b_o  -> fp32
    gemm_split<false><<<dim3(DMODEL / 128, M / 128), 256, 0, stream>>>(
        vHi, vLo, wo, b_o, out, M, DMODEL, DMODEL);
}

// Round 7
// 200.718 us; speedup vs baseline: 2.0727x; 1.3961x over previous
//
#include <hip/hip_runtime.h>
#include <hip/hip_bf16.h>
#include <math.h>

// Problem constants
#define BATCH 2
#define SLEN  2048
#define DIN   1024
#define DMODEL 1024
#define NHEAD 16
#define HD    64
#define E3    3072   // 3*DMODEL, row width of qkv

typedef unsigned short us;
typedef _Float16 f16;
typedef __attribute__((ext_vector_type(8))) _Float16 f16x8;
typedef __attribute__((ext_vector_type(8))) unsigned short us8;
typedef __attribute__((ext_vector_type(4))) unsigned short us4;
typedef __attribute__((ext_vector_type(4))) float f32x4;
typedef __attribute__((ext_vector_type(16))) float f32x16;

// 0.125 (1/sqrt(HD)) * log2(e): folded into Q at qkv-GEMM epilogue so the
// attention softmax is a bare exp2 of the raw MFMA score.
#define QSCALE 0.18033688011112042f

__device__ __forceinline__ us f16bits(float x) {
    const f16 h = (f16)x;
    return __builtin_bit_cast(us, h);
}

// async 16B global->LDS (lane i deposits at ldsbase + i*16)
#define GLL16(g, l)                                                                     \
    __builtin_amdgcn_global_load_lds((const __attribute__((address_space(1))) unsigned int*)(g), \
                                     (__attribute__((address_space(3))) unsigned int*)(l), 16, 0, 0)

// ---------------- fp32 -> fp16 for x, w_qkv, w_o in one launch ----------------
__global__ __launch_bounds__(256) void cvt3_f16(
    const float* __restrict__ x, us* __restrict__ ox, int nx,
    const float* __restrict__ wq, us* __restrict__ owq, int nq,
    const float* __restrict__ wo, us* __restrict__ owo)
{
    int i = (blockIdx.x * 256 + threadIdx.x) * 8;
    const float* s;
    us* o;
    if (i < nx)           { s = x;  o = ox; }
    else if (i < nx + nq) { s = wq; o = owq; i -= nx; }
    else                  { s = wo; o = owo; i -= nx + nq; }
    const float4 f0 = *(const float4*)&s[i];
    const float4 f1 = *(const float4*)&s[i + 4];
    const float v[8] = {f0.x, f0.y, f0.z, f0.w, f1.x, f1.y, f1.z, f1.w};
    us8 h;
#pragma unroll
    for (int j = 0; j < 8; ++j) h[j] = f16bits(v[j]);
    *(us8*)&o[i] = h;
}

// ---------------- single-fp16 MFMA GEMM ----------------
// C[M,N] = A[M,K] * B[N,K]^T + bias[N], all fp16 inputs, fp32 accumulate.
// 128x128 tile, BK=32, 256 thr = 4 waves (2x2), 4x4 16x16 tiles per wave.
// QKV_OUT: write fp16 and pre-scale Q columns (col%192 < 64) by QSCALE.
template <bool QKV_OUT>
__global__ __launch_bounds__(256) void gemm_f16(
    const us* __restrict__ Am, const us* __restrict__ Bm,
    const float* __restrict__ bias, void* __restrict__ Cout,
    int M, int N, int K)
{
    __shared__ __align__(16) us As[128 * 32];
    __shared__ __align__(16) us Bs[128 * 32];

    const int t    = threadIdx.x;
    const int lane = t & 63;
    const int w    = t >> 6;
    const int ml   = lane & 15;
    const int quad = lane >> 4;
    const int wm   = w >> 1;
    const int wn   = w & 1;

    const int m0 = blockIdx.y * 128;
    const int n0 = blockIdx.x * 128;

    const int srow = (lane >> 2);
    const int scol = (lane & 3) * 8;

    const us* pA = Am + (size_t)(m0 + w * 32 + srow) * K + scol;
    const us* pB = Bm + (size_t)(n0 + w * 32 + srow) * K + scol;
    const size_t rstep = (size_t)16 * K;

    us* lA0 = &As[(w * 32) * 32];
    us* lA1 = &As[(w * 32 + 16) * 32];
    us* lB0 = &Bs[(w * 32) * 32];
    us* lB1 = &Bs[(w * 32 + 16) * 32];

    f32x4 acc[4][4];
#pragma unroll
    for (int i = 0; i < 4; ++i)
#pragma unroll
        for (int j = 0; j < 4; ++j) {
            acc[i][j][0] = 0.f; acc[i][j][1] = 0.f; acc[i][j][2] = 0.f; acc[i][j][3] = 0.f;
        }

    for (int k0 = 0; k0 < K; k0 += 32) {
        __syncthreads();
        GLL16(pA + k0, lA0); GLL16(pA + k0 + rstep, lA1);
        GLL16(pB + k0, lB0); GLL16(pB + k0 + rstep, lB1);
        __syncthreads();

        f16x8 a[4];
#pragma unroll
        for (int i = 0; i < 4; ++i)
            a[i] = __builtin_bit_cast(f16x8, *(const us8*)&As[(wm * 64 + i * 16 + ml) * 32 + quad * 8]);
#pragma unroll
        for (int j = 0; j < 4; ++j) {
            const f16x8 b = __builtin_bit_cast(f16x8, *(const us8*)&Bs[(wn * 64 + j * 16 + ml) * 32 + quad * 8]);
#pragma unroll
            for (int i = 0; i < 4; ++i)
                acc[i][j] = __builtin_amdgcn_mfma_f32_16x16x32_f16(a[i], b, acc[i][j], 0, 0, 0);
        }
    }

    float bj[4], cs[4];
#pragma unroll
    for (int j = 0; j < 4; ++j) {
        const int col = n0 + wn * 64 + j * 16 + ml;
        bj[j] = bias[col];
        cs[j] = (QKV_OUT && (col % 192) < 64) ? QSCALE : 1.0f;
    }

#pragma unroll
    for (int i = 0; i < 4; ++i) {
#pragma unroll
        for (int r = 0; r < 4; ++r) {
            const size_t rowoff = (size_t)(m0 + wm * 64 + i * 16 + quad * 4 + r) * N;
#pragma unroll
            for (int j = 0; j < 4; ++j) {
                const int col = n0 + wn * 64 + j * 16 + ml;
                const float v = (acc[i][j][r] + bj[j]) * cs[j];
                if (QKV_OUT) ((us*)Cout)[rowoff + col] = f16bits(v);
                else         ((float*)Cout)[rowoff + col] = v;
            }
        }
    }
}

// ---------------- MFMA flash attention, 32x32 shape, transposed-score ----------------
// 4 waves x 32 q = 128 queries/block; 64-key chunks; Q pre-scaled so p = exp2(score).
// S^T = K.Q^T via mfma_f32_32x32x16_f16 (A=K rows, B=Q regs). P stored [q][key]
// (packed us4 per reg-quad), read back as B-frags for O^T = V^T.P^T.
// l = per-lane partial sums + one shfl_xor(32). Next chunk's K/V prefetched into
// registers during compute. Wave w's P scratch = its own Q rows [32w,32w+32).
// Fragment maps (32x32x16): A[m=lane&31][k=(lane>>5)*8+j]; B[k=(lane>>5)*8+j][n=lane&31];
// C/D: col=lane&31, row=(reg&3)+8*(reg>>2)+4*(lane>>5)  [m74/m101-verified].
#define ABQ 128
#define ACH 64
#define NCH (SLEN / ACH)
#define LQA 72   // LDS row stride in fp16 elems (36 words)

__global__ __launch_bounds__(256) void attn_mfma(
    const us* __restrict__ qkvh, us* __restrict__ vals)
{
    __shared__ __align__(16) us QPs[ABQ * LQA];  // Q tile, then per-wave P scratch
    __shared__ __align__(16) us Ks[ACH * LQA];   // K rows [key][dim]
    __shared__ __align__(16) us Vt[HD * LQA];    // V^T [dim][key]

    const int t    = threadIdx.x;
    const int lane = t & 63;
    const int w    = t >> 6;        // wave 0..3
    const int m32  = lane & 31;
    const int half = lane >> 5;

    const int bh = blockIdx.y;
    const int b  = bh >> 4;
    const int h  = bh & 15;
    const int q0 = blockIdx.x * ABQ;

    const size_t base = (size_t)b * SLEN * E3;
    const int qoff = h * 192;

    // ---- stage Q (128 q x 64 d): 32 elems / thread ----
    {
        const int row = t >> 1;
        const int c0  = (t & 1) * 32;
        const us* g = &qkvh[base + (size_t)(q0 + row) * E3 + qoff + c0];
#pragma unroll
        for (int s = 0; s < 4; ++s)
            *(us8*)&QPs[row * LQA + c0 + s * 8] = *(const us8*)(g + s * 8);
    }
    __syncthreads();

    // Q B-frags: B[k=dim][n=q], q = w*32 + m32 (wave reads only its own rows)
    f16x8 aq[4];
#pragma unroll
    for (int s = 0; s < 4; ++s)
        aq[s] = __builtin_bit_cast(f16x8, *(const us8*)&QPs[(w * 32 + m32) * LQA + half * 8 + 16 * s]);

    // staging maps
    const int krA = t >> 2;         // K: 0..63, 16 dims/thread
    const int ksA = (t & 3) * 16;
    const int krB = t & 63;         // V: all 64 keys per wave (conflict-free scatter)
    const int ksB = w * 16;

    // prefetch chunk 0 into regs
    us8 kk0, kk1, vv0, vv1;
    {
        const us* gK = &qkvh[base + (size_t)(krA) * E3 + qoff + 64 + ksA];
        kk0 = *(const us8*)gK; kk1 = *(const us8*)(gK + 8);
        const us* gV = &qkvh[base + (size_t)(krB) * E3 + qoff + 128 + ksB];
        vv0 = *(const us8*)gV; vv1 = *(const us8*)(gV + 8);
    }

    f32x16 O[2];
#pragma unroll
    for (int dt = 0; dt < 2; ++dt)
#pragma unroll
        for (int r = 0; r < 16; ++r) O[dt][r] = 0.f;
    float lpart = 0.f;

    const int prow = (w * 32 + m32) * LQA;   // this lane's P row (q = w*32+m32)

    for (int c = 0; c < NCH; ++c) {
        __syncthreads();   // previous chunk's Ks/Vt fully consumed
        // ---- regs -> LDS ----
        *(us8*)&Ks[krA * LQA + ksA]     = kk0;
        *(us8*)&Ks[krA * LQA + ksA + 8] = kk1;
#pragma unroll
        for (int j = 0; j < 8; ++j) Vt[(ksB + j) * LQA + krB]     = vv0[j];
#pragma unroll
        for (int j = 0; j < 8; ++j) Vt[(ksB + 8 + j) * LQA + krB] = vv1[j];
        __syncthreads();
        // ---- prefetch next chunk (latency hidden behind compute) ----
        if (c + 1 < NCH) {
            const us* gK = &qkvh[base + (size_t)((c + 1) * ACH + krA) * E3 + qoff + 64 + ksA];
            kk0 = *(const us8*)gK; kk1 = *(const us8*)(gK + 8);
            const us* gV = &qkvh[base + (size_t)((c + 1) * ACH + krB) * E3 + qoff + 128 + ksB];
            vv0 = *(const us8*)gV; vv1 = *(const us8*)(gV + 8);
        }

        // ---- S^T = K.Q^T per key-tile; exp2; packed us4 P store ----
#pragma unroll
        for (int kt = 0; kt < 2; ++kt) {
            f32x16 z;
#pragma unroll
            for (int r = 0; r < 16; ++r) z[r] = 0.f;
#pragma unroll
            for (int s = 0; s < 4; ++s) {
                const f16x8 ak = __builtin_bit_cast(f16x8, *(const us8*)&Ks[(kt * 32 + m32) * LQA + half * 8 + 16 * s]);
                z = __builtin_amdgcn_mfma_f32_32x32x16_f16(ak, aq[s], z, 0, 0, 0);
            }
            // reg r: key = kt*32 + (r&3) + 8*(r>>2) + 4*half, q = m32
#pragma unroll
            for (int g = 0; g < 4; ++g) {
                us4 pp;
#pragma unroll
                for (int r2 = 0; r2 < 4; ++r2) {
                    const float p = __builtin_amdgcn_exp2f(z[g * 4 + r2]);
                    lpart += p;
                    pp[r2] = f16bits(p);
                }
                *(us4*)&QPs[prow + kt * 32 + 8 * g + 4 * half] = pp;
            }
        }

        // ---- P^T B-frags; O^T += V^T.P^T ----
        f16x8 pf[4];
#pragma unroll
        for (int s = 0; s < 4; ++s)
            pf[s] = __builtin_bit_cast(f16x8, *(const us8*)&QPs[prow + half * 8 + 16 * s]);
#pragma unroll
        for (int dt = 0; dt < 2; ++dt) {
#pragma unroll
            for (int s = 0; s < 4; ++s) {
                const f16x8 av = __builtin_bit_cast(f16x8, *(const us8*)&Vt[(dt * 32 + m32) * LQA + half * 8 + 16 * s]);
                O[dt] = __builtin_amdgcn_mfma_f32_32x32x16_f16(av, pf[s], O[dt], 0, 0, 0);
            }
        }
    }

    // ---- epilogue: l = lpart + partner half; normalize; fp16 us4 stores ----
    const float l  = lpart + __shfl_xor(lpart, 32);
    const float rl = 1.0f / l;
    const int sq = q0 + w * 32 + m32;
    const size_t rowbase = (size_t)(b * SLEN + sq) * DMODEL + h * HD;
#pragma unroll
    for (int dt = 0; dt < 2; ++dt) {
#pragma unroll
        for (int g = 0; g < 4; ++g) {
            us4 o4;
#pragma unroll
            for (int r2 = 0; r2 < 4; ++r2) o4[r2] = f16bits(O[dt][g * 4 + r2] * rl);
            *(us4*)&vals[rowbase + dt * 32 + 8 * g + 4 * half] = o4;
        }
    }
}

// ---------------- launch ----------------
extern "C" void kernel_launch(void* const* d_in, const int* in_sizes, int n_in,
                              void* d_out, int out_size, void* d_ws, size_t ws_size,
                              hipStream_t stream) {
    const float* x     = (const float*)d_in[0];
    const float* w_qkv = (const float*)d_in[1];
    const float* b_qkv = (const float*)d_in[2];
    const float* w_o   = (const float*)d_in[3];
    const float* b_o   = (const float*)d_in[4];
    float* out = (float*)d_out;

    const int M   = BATCH * SLEN;        // 4096
    const int XN  = M * DIN;             // 4,194,304
    const int WQN = E3 * DIN;            // 3,145,728
    const int WON = DMODEL * DMODEL;     // 1,048,576
    const size_t QKVN = (size_t)BATCH * SLEN * E3;

    us* qkvh = (us*)d_ws;                // fp16 qkv [QKVN]
    us* xh   = qkvh + QKVN;              // fp16 x [XN], reused for vals
    us* wq   = xh + XN;                  // fp16 w_qkv [WQN]
    us* wo   = wq + WQN;                 // fp16 w_o [WON]

    // 1) fp32 -> fp16 conversions, one launch
    cvt3_f16<<<dim3((XN + WQN + WON) / 2048), 256, 0, stream>>>(
        x, xh, XN, w_qkv, wq, WQN, w_o, wo);

    // 2) qkv = x @ w_qkv^T + b_qkv -> fp16 (Q cols pre-scaled by QSCALE)
    gemm_f16<true><<<dim3(E3 / 128, M / 128), 256, 0, stream>>>(
        xh, wq, b_qkv, qkvh, M, E3, DIN);

    // 3) attention -> vals fp16 (reuse x plane; x is dead)
    us* vals = xh;
    attn_mfma<<<dim3(SLEN / ABQ, BATCH * NHEAD), 256, 0, stream>>>(qkvh, vals);

    // 4) out = vals @ w_o^T + b_o -> fp32
    gemm_f16<false><<<dim3(DMODEL / 128, M / 128), 256, 0, stream>>>(
        vals, wo, b_o, out, M, DMODEL, DMODEL);
}